// Round 1
// baseline (9349.307 us; speedup 1.0000x reference)
//
#include <hip/hip_runtime.h>
#include <cstdint>
#include <cstddef>

// LSTM: IC=HC=512, L=2, T=512, BS=64.  out = [T,64,512] fp32, hs/cs = [2,64,512] fp32.
// Strategy: persistent per-layer kernel, 64 WGs (8 hidden-cols each, all 4 gates),
// weight slice resident in LDS as B-fragments, bf16 MFMA 16x16x32, fp32 gates,
// device-scope monotone-counter barrier per timestep.

#define T_STEPS 512
#define NWG 64
#define WROW 1032   // LDS row stride (bf16 elems): 1024 + 8 pad -> 2-way bank aliasing (free)

typedef float f32x4 __attribute__((ext_vector_type(4)));
typedef short s16x8 __attribute__((ext_vector_type(8)));

__device__ __forceinline__ unsigned short f2bf(float f) {
    unsigned int u = __builtin_bit_cast(unsigned int, f);
    u += 0x7FFFu + ((u >> 16) & 1u);          // round-to-nearest-even
    return (unsigned short)(u >> 16);
}
__device__ __forceinline__ float sig_(float x)  { return 1.0f / (1.0f + __expf(-x)); }
__device__ __forceinline__ float tanh_(float x) { return 1.0f - 2.0f / (__expf(2.0f * x) + 1.0f); }

// ---- prep kernels -------------------------------------------------------

// x fp32 -> bf16, 8 elems/thread.  n = 16,777,216 exactly covered by 8192x256.
__global__ void k_conv_bf16(const float* __restrict__ src, unsigned short* __restrict__ dst) {
    int i = (blockIdx.x * 256 + threadIdx.x) * 8;
    float4 a = *(const float4*)(src + i);
    float4 b = *(const float4*)(src + i + 4);
    s16x8 o;
    o[0]=(short)f2bf(a.x); o[1]=(short)f2bf(a.y); o[2]=(short)f2bf(a.z); o[3]=(short)f2bf(a.w);
    o[4]=(short)f2bf(b.x); o[5]=(short)f2bf(b.y); o[6]=(short)f2bf(b.z); o[7]=(short)f2bf(b.w);
    *(s16x8*)(dst + i) = o;
}

// W [1024][2048] fp32 -> WT [2048][1024] bf16 (k-contiguous rows). z picks layer.
__global__ void k_transpose_w(const float* __restrict__ W0, const float* __restrict__ W1,
                              unsigned short* __restrict__ WT0, unsigned short* __restrict__ WT1) {
    __shared__ unsigned short tile[32][33];
    const float* W = blockIdx.z ? W1 : W0;
    unsigned short* WT = blockIdx.z ? WT1 : WT0;
    int n0 = blockIdx.x * 32, k0 = blockIdx.y * 32;
    int tx = threadIdx.x, ty = threadIdx.y;       // (32,8)
    #pragma unroll
    for (int i = 0; i < 4; i++)
        tile[ty + i*8][tx] = f2bf(W[(size_t)(k0 + ty + i*8) * 2048 + n0 + tx]);
    __syncthreads();
    #pragma unroll
    for (int i = 0; i < 4; i++)
        WT[(size_t)(n0 + ty + i*8) * 1024 + k0 + tx] = tile[tx][ty + i*8];
}

// h0 [2][1][512] fp32 -> broadcast over batch into packed layout [jblock][b][8] bf16.
__global__ void k_hinit(const float* __restrict__ h0, unsigned short* __restrict__ hi0,
                        unsigned short* __restrict__ hi1) {
    int idx = blockIdx.x * 256 + threadIdx.x;   // 65536 total
    int layer = idx >> 15;
    int r = idx & 32767;
    int b = r >> 9;
    int j = r & 511;
    unsigned short v = f2bf(h0[layer * 512 + j]);
    unsigned short* d = layer ? hi1 : hi0;
    d[(size_t)((j >> 3) * 64 + b) * 8 + (j & 7)] = v;
}

// ---- persistent recurrence kernel ---------------------------------------
// WG w owns hidden cols j0=8w..8w+7 (all 4 gates = 32 gate-cols).
// LDS Wl[32][WROW]: rows 0-7 f, 8-15 i, 16-23 o, 24-31 g; Wl[c][k] = W[k][gatecol].
// h sequences stored packed: [t][jblock(64)][b(64)][8] bf16 — every step's reads are
// first-touch addresses (no stale per-XCD-L2 copies possible), writes are WG-exclusive
// 1 KB blocks (no cross-XCD false sharing).
template<int IS_L1>
__global__ __launch_bounds__(256, 1) void k_lstm_layer(
    const unsigned short* __restrict__ xseq,   // L0: [t*64+b][512] bf16; L1: packed h0seq
    const unsigned short* __restrict__ hinit,  // packed [jblock][b][8]
    const unsigned short* __restrict__ WT,     // [2048][1024] bf16
    const float* __restrict__ bias,            // [2048] fp32
    const float* __restrict__ c0,              // [512] fp32 (this layer)
    unsigned short* __restrict__ hseq,         // packed [T][...] bf16 (this layer's h out)
    float* __restrict__ out,                   // L1: d_out [t*64+b][512] fp32
    float* __restrict__ hs_out,                // d_out hs slice [b][512]
    float* __restrict__ cs_out,                // d_out cs slice [b][512]
    unsigned int* __restrict__ cnt)
{
    __shared__ unsigned short Wl[32][WROW];
    const int tid = threadIdx.x;
    const int j0 = blockIdx.x * 8;

    // Load weight slice: 32 rows x 1024 bf16, coalesced 16B chunks.
    #pragma unroll
    for (int it = 0; it < 16; it++) {
        int idx = it * 256 + tid;          // 0..4095 = 32 rows * 128 chunks
        int row = idx >> 7;
        int ch  = idx & 127;
        int cc_ = row & 15;
        int gate = (row >> 4) * 2 + (cc_ >> 3);          // 0:f 1:i 2:o 3:g
        int gr = gate * 512 + j0 + (cc_ & 7);            // W column index
        *(s16x8*)(&Wl[row][ch * 8]) = *(const s16x8*)(WT + (size_t)gr * 1024 + ch * 8);
    }
    __syncthreads();

    const int lane = tid & 63;
    const int wv = tid >> 6;          // wave: batch rows [16wv,16wv+16)
    const int q = lane >> 4;          // quad
    const int cc = lane & 15;         // MFMA col
    const int arow = wv * 16 + cc;    // A-frag batch row
    const int jj = j0 + (cc & 7);     // hidden col
    const int bb = wv * 16 + q * 4;   // C/D batch row base

    const float bias0 = (cc < 8) ? bias[jj] : bias[512 + jj];
    const float bias1 = (cc < 8) ? bias[1024 + jj] : bias[1536 + jj];
    float cst[4];
    {
        float ci = c0[jj];
        cst[0] = cst[1] = cst[2] = cst[3] = ci;
    }

    for (int t = 0; t < T_STEPS; t++) {
        s16x8 af[32];
        // x-part fragments (k 0..511)
        if (IS_L1) {
            const unsigned short* xb = xseq + (size_t)t * 32768;   // packed
            #pragma unroll
            for (int kk = 0; kk < 16; kk++)
                af[kk] = *(const s16x8*)(xb + ((kk * 4 + q) * 64 + arow) * 8);
        } else {
            const unsigned short* xb = xseq + (size_t)(t * 64 + arow) * 512 + q * 8;
            #pragma unroll
            for (int kk = 0; kk < 16; kk++)
                af[kk] = *(const s16x8*)(xb + kk * 32);
        }
        // h-part fragments (k 512..1023), packed layout
        {
            const unsigned short* hb = (t == 0) ? hinit : (hseq + (size_t)(t - 1) * 32768);
            #pragma unroll
            for (int kk = 0; kk < 16; kk++)
                af[16 + kk] = *(const s16x8*)(hb + ((kk * 4 + q) * 64 + arow) * 8);
        }

        f32x4 acc0  = {bias0, bias0, bias0, bias0};   // tile0: [f|i]
        f32x4 acc1  = {bias1, bias1, bias1, bias1};   // tile1: [o|g]
        f32x4 acc0b = {0.f, 0.f, 0.f, 0.f};
        f32x4 acc1b = {0.f, 0.f, 0.f, 0.f};
        #pragma unroll
        for (int kk = 0; kk < 32; kk += 2) {
            s16x8 w00 = *(const s16x8*)(&Wl[cc][kk * 32 + q * 8]);
            s16x8 w10 = *(const s16x8*)(&Wl[16 + cc][kk * 32 + q * 8]);
            acc0  = __builtin_amdgcn_mfma_f32_16x16x32_bf16(af[kk], w00, acc0, 0, 0, 0);
            acc1  = __builtin_amdgcn_mfma_f32_16x16x32_bf16(af[kk], w10, acc1, 0, 0, 0);
            s16x8 w01 = *(const s16x8*)(&Wl[cc][(kk + 1) * 32 + q * 8]);
            s16x8 w11 = *(const s16x8*)(&Wl[16 + cc][(kk + 1) * 32 + q * 8]);
            acc0b = __builtin_amdgcn_mfma_f32_16x16x32_bf16(af[kk + 1], w01, acc0b, 0, 0, 0);
            acc1b = __builtin_amdgcn_mfma_f32_16x16x32_bf16(af[kk + 1], w11, acc1b, 0, 0, 0);
        }
        acc0 = acc0 + acc0b;
        acc1 = acc1 + acc1b;

        unsigned short* hdst = hseq + (size_t)t * 32768;
        #pragma unroll
        for (int r = 0; r < 4; r++) {
            float z0 = acc0[r], z1 = acc1[r];
            float p0 = __shfl_xor(z0, 8, 64);
            float p1 = __shfl_xor(z1, 8, 64);
            float zf = (cc < 8) ? z0 : p0;
            float zi = (cc < 8) ? p0 : z0;
            float zo = (cc < 8) ? z1 : p1;
            float zg = (cc < 8) ? p1 : z1;
            float fg = sig_(zf + 1.0f);        // FORGET_BIAS
            float ig = sig_(zi);
            float og = sig_(zo);
            float gg = tanh_(zg);
            float cn = cst[r] * fg + gg * ig;
            cst[r] = cn;
            float hv = og * tanh_(cn);
            int b = bb + r;
            if (cc < 8)
                hdst[(size_t)(blockIdx.x * 64 + b) * 8 + (cc & 7)] = f2bf(hv);
            if (IS_L1 && cc >= 8)
                out[(size_t)(t * 64 + b) * 512 + jj] = hv;
            if (t == T_STEPS - 1) {
                if (cc < 8) hs_out[(size_t)b * 512 + jj] = hv;
                else        cs_out[(size_t)b * 512 + jj] = cn;
            }
        }

        // device-wide step barrier (monotone counter; release drains L2 writeback)
        if (t < T_STEPS - 1) {
            __syncthreads();   // drains vmcnt: all WG stores at L2
            if (tid == 0) {
                __hip_atomic_fetch_add(cnt, 1u, __ATOMIC_RELEASE, __HIP_MEMORY_SCOPE_AGENT);
                const unsigned int target = (unsigned int)(NWG * (t + 1));
                while (__hip_atomic_load(cnt, __ATOMIC_RELAXED, __HIP_MEMORY_SCOPE_AGENT) < target)
                    __builtin_amdgcn_s_sleep(2);
                __builtin_amdgcn_fence(__ATOMIC_ACQUIRE, "agent");
            }
            __syncthreads();
        }
    }
}

// ---- launch -------------------------------------------------------------

extern "C" void kernel_launch(void* const* d_in, const int* in_sizes, int n_in,
                              void* d_out, int out_size, void* d_ws, size_t ws_size,
                              hipStream_t stream) {
    const float* x  = (const float*)d_in[0];
    const float* W0 = (const float*)d_in[1];
    const float* b0 = (const float*)d_in[2];
    const float* W1 = (const float*)d_in[3];
    const float* b1 = (const float*)d_in[4];
    const float* h0 = (const float*)d_in[5];
    const float* c0 = (const float*)d_in[6];
    float* out = (float*)d_out;

    char* ws = (char*)d_ws;
    unsigned short* xb  = (unsigned short*)(ws);                               // 33,554,432 B
    unsigned short* h0s = (unsigned short*)(ws + 33554432);                    // 33,554,432 B
    unsigned short* h1s = (unsigned short*)(ws + 2 * 33554432);                // 33,554,432 B
    unsigned short* WT0 = (unsigned short*)(ws + 3 * 33554432);                //  4,194,304 B
    unsigned short* WT1 = (unsigned short*)(ws + 3 * 33554432 + 4194304);      //  4,194,304 B
    unsigned short* hi0 = (unsigned short*)(ws + 3 * 33554432 + 2 * 4194304);            // 65,536 B
    unsigned short* hi1 = (unsigned short*)(ws + 3 * 33554432 + 2 * 4194304 + 65536);    // 65,536 B
    unsigned int*   cnt = (unsigned int*)(ws + 3 * 33554432 + 2 * 4194304 + 2 * 65536);  // counters

    hipMemsetAsync(cnt, 0, 256, stream);
    k_conv_bf16<<<8192, 256, 0, stream>>>(x, xb);
    k_transpose_w<<<dim3(64, 32, 2), dim3(32, 8), 0, stream>>>(W0, W1, WT0, WT1);
    k_hinit<<<256, 256, 0, stream>>>(h0, hi0, hi1);

    float* hs = out + 16777216;            // [2][64][512]
    float* cs = hs + 65536;                // [2][64][512]
    k_lstm_layer<0><<<NWG, 256, 0, stream>>>(xb,  hi0, WT0, b0, c0,       h0s, (float*)nullptr, hs,        cs,        cnt);
    k_lstm_layer<1><<<NWG, 256, 0, stream>>>(h0s, hi1, WT1, b1, c0 + 512, h1s, out,             hs + 32768, cs + 32768, cnt + 1);
}

// Round 2
// 2887.461 us; speedup vs baseline: 3.2379x; 3.2379x over previous
//
#include <hip/hip_runtime.h>
#include <cstdint>
#include <cstddef>

// LSTM: IC=HC=512, L=2, T=512, BS=64.  out = [T,64,512] fp32, hs/cs = [2,64,512] fp32.
// R1: fused 2-layer persistent kernel (128 WGs), pipeline skew 1 step.
//     Recurrent h exchange via relaxed agent-scope atomics (sc0 sc1 -> MALL-coherent,
//     NO L2 writeback/invalidate fences).  x/weights stay normally cached.

#define T_STEPS 512
#define WROW 1032   // LDS row stride (bf16 elems): 1024 + 8 pad

typedef float f32x4 __attribute__((ext_vector_type(4)));
typedef short s16x8 __attribute__((ext_vector_type(8)));

__device__ __forceinline__ unsigned short f2bf(float f) {
    unsigned int u = __builtin_bit_cast(unsigned int, f);
    u += 0x7FFFu + ((u >> 16) & 1u);          // round-to-nearest-even
    return (unsigned short)(u >> 16);
}
__device__ __forceinline__ float sig_(float x)  { return 1.0f / (1.0f + __expf(-x)); }
__device__ __forceinline__ float tanh_(float x) { return 1.0f - 2.0f / (__expf(2.0f * x) + 1.0f); }

// Coherent (agent-scope, L2-bypassing) 16B load/store as 2x8B relaxed atomics.
__device__ __forceinline__ s16x8 ldc(const unsigned short* p) {
    unsigned long long lo = __hip_atomic_load((unsigned long long*)p,     __ATOMIC_RELAXED, __HIP_MEMORY_SCOPE_AGENT);
    unsigned long long hi = __hip_atomic_load((unsigned long long*)p + 1, __ATOMIC_RELAXED, __HIP_MEMORY_SCOPE_AGENT);
    ulonglong2 u; u.x = lo; u.y = hi;
    return __builtin_bit_cast(s16x8, u);
}
__device__ __forceinline__ void stc(unsigned short* p, s16x8 v) {
    ulonglong2 u = __builtin_bit_cast(ulonglong2, v);
    __hip_atomic_store((unsigned long long*)p,     u.x, __ATOMIC_RELAXED, __HIP_MEMORY_SCOPE_AGENT);
    __hip_atomic_store((unsigned long long*)p + 1, u.y, __ATOMIC_RELAXED, __HIP_MEMORY_SCOPE_AGENT);
}

// ---- prep kernels -------------------------------------------------------

__global__ void k_conv_bf16(const float* __restrict__ src, unsigned short* __restrict__ dst) {
    int i = (blockIdx.x * 256 + threadIdx.x) * 8;
    float4 a = *(const float4*)(src + i);
    float4 b = *(const float4*)(src + i + 4);
    s16x8 o;
    o[0]=(short)f2bf(a.x); o[1]=(short)f2bf(a.y); o[2]=(short)f2bf(a.z); o[3]=(short)f2bf(a.w);
    o[4]=(short)f2bf(b.x); o[5]=(short)f2bf(b.y); o[6]=(short)f2bf(b.z); o[7]=(short)f2bf(b.w);
    *(s16x8*)(dst + i) = o;
}

__global__ void k_transpose_w(const float* __restrict__ W0, const float* __restrict__ W1,
                              unsigned short* __restrict__ WT0, unsigned short* __restrict__ WT1) {
    __shared__ unsigned short tile[32][33];
    const float* W = blockIdx.z ? W1 : W0;
    unsigned short* WT = blockIdx.z ? WT1 : WT0;
    int n0 = blockIdx.x * 32, k0 = blockIdx.y * 32;
    int tx = threadIdx.x, ty = threadIdx.y;       // (32,8)
    #pragma unroll
    for (int i = 0; i < 4; i++)
        tile[ty + i*8][tx] = f2bf(W[(size_t)(k0 + ty + i*8) * 2048 + n0 + tx]);
    __syncthreads();
    #pragma unroll
    for (int i = 0; i < 4; i++)
        WT[(size_t)(n0 + ty + i*8) * 1024 + k0 + tx] = tile[tx][ty + i*8];
}

__global__ void k_hinit(const float* __restrict__ h0, unsigned short* __restrict__ hi0,
                        unsigned short* __restrict__ hi1) {
    int idx = blockIdx.x * 256 + threadIdx.x;   // 65536 total
    int layer = idx >> 15;
    int r = idx & 32767;
    int b = r >> 9;
    int j = r & 511;
    unsigned short v = f2bf(h0[layer * 512 + j]);
    unsigned short* d = layer ? hi1 : hi0;
    d[(size_t)((j >> 3) * 64 + b) * 8 + (j & 7)] = v;
}

// ---- fused persistent recurrence kernel ---------------------------------
// blockIdx 0..63 = layer 0, 64..127 = layer 1; wg = blockIdx&63 owns hidden cols 8wg..8wg+7.
// h sequences packed [t][jblock(64)][b(64)][8] bf16, coherent (MALL) accesses only.
// Arrival counters split 4-way per layer to cut same-line atomic serialization.
__global__ __launch_bounds__(256, 1) void k_lstm_fused(
    const unsigned short* __restrict__ xb,
    const unsigned short* __restrict__ hi0, const unsigned short* __restrict__ hi1,
    const unsigned short* __restrict__ WT0, const unsigned short* __restrict__ WT1,
    const float* __restrict__ b0, const float* __restrict__ b1,
    const float* __restrict__ c0,
    unsigned short* __restrict__ h0s, unsigned short* __restrict__ h1s,
    float* __restrict__ out, float* __restrict__ hs, float* __restrict__ cs,
    unsigned int* __restrict__ cnt)
{
    __shared__ unsigned short Wl[32][WROW];
    __shared__ unsigned short hstage[64][8];

    const int isl1 = (int)(blockIdx.x >> 6);
    const int wg   = (int)(blockIdx.x & 63);
    const int tid  = threadIdx.x;
    const int j0   = wg * 8;

    const unsigned short* WT    = isl1 ? WT1 : WT0;
    const float*          bias  = isl1 ? b1  : b0;
    const float*          c0l   = c0 + isl1 * 512;
    const unsigned short* hinit = isl1 ? hi1 : hi0;
    unsigned short*       hseq  = isl1 ? h1s : h0s;
    unsigned int* my_cnt   = cnt + isl1 * 64;   // 4 sub-counters at stride 16 u32 (64B lines)
    unsigned int* prod_cnt = cnt;               // layer0's counters

    // Load weight slice: 32 rows x 1024 bf16, coalesced 16B chunks.
    #pragma unroll
    for (int it = 0; it < 16; it++) {
        int idx = it * 256 + tid;
        int row = idx >> 7;
        int ch  = idx & 127;
        int cc_ = row & 15;
        int gate = (row >> 4) * 2 + (cc_ >> 3);          // 0:f 1:i 2:o 3:g
        int gr = gate * 512 + j0 + (cc_ & 7);
        *(s16x8*)(&Wl[row][ch * 8]) = *(const s16x8*)(WT + (size_t)gr * 1024 + ch * 8);
    }
    __syncthreads();

    const int lane = tid & 63;
    const int wv = tid >> 6;
    const int q = lane >> 4;
    const int cc = lane & 15;
    const int arow = wv * 16 + cc;
    const int jj = j0 + (cc & 7);
    const int bb = wv * 16 + q * 4;

    const float bias0 = (cc < 8) ? bias[jj] : bias[512 + jj];
    const float bias1 = (cc < 8) ? bias[1024 + jj] : bias[1536 + jj];
    float cst[4];
    {
        float ci = c0l[jj];
        cst[0] = cst[1] = cst[2] = cst[3] = ci;
    }

    for (int t = 0; t < T_STEPS; t++) {
        s16x8 af[32];
        // layer0: x fragments are pure input -> load BEFORE the wait (overlaps spin)
        if (!isl1) {
            const unsigned short* xp = xb + (size_t)(t * 64 + arow) * 512 + q * 8;
            #pragma unroll
            for (int kk = 0; kk < 16; kk++)
                af[kk] = *(const s16x8*)(xp + kk * 32);
        }

        // dependency wait: lanes 0..3 poll the 4 sub-counters in parallel
        if (isl1) {
            if (tid < 4) {
                unsigned int tgt = 16u * (unsigned int)(t + 1);
                while (__hip_atomic_load(prod_cnt + tid * 16, __ATOMIC_RELAXED, __HIP_MEMORY_SCOPE_AGENT) < tgt)
                    __builtin_amdgcn_s_sleep(1);
                if (t > 0) {
                    unsigned int tgt2 = 16u * (unsigned int)t;
                    while (__hip_atomic_load(my_cnt + tid * 16, __ATOMIC_RELAXED, __HIP_MEMORY_SCOPE_AGENT) < tgt2)
                        __builtin_amdgcn_s_sleep(1);
                }
            }
            __syncthreads();
        } else if (t > 0) {
            if (tid < 4) {
                unsigned int tgt = 16u * (unsigned int)t;
                while (__hip_atomic_load(my_cnt + tid * 16, __ATOMIC_RELAXED, __HIP_MEMORY_SCOPE_AGENT) < tgt)
                    __builtin_amdgcn_s_sleep(1);
            }
            __syncthreads();
        }

        // layer1: x = layer0's h at step t (coherent)
        if (isl1) {
            const unsigned short* xp = h0s + (size_t)t * 32768;
            #pragma unroll
            for (int kk = 0; kk < 16; kk++)
                af[kk] = ldc(xp + ((size_t)(kk * 4 + q) * 64 + arow) * 8);
        }
        // own h at step t-1 (coherent)
        {
            const unsigned short* hb = t ? (hseq + (size_t)(t - 1) * 32768) : hinit;
            #pragma unroll
            for (int kk = 0; kk < 16; kk++)
                af[16 + kk] = ldc(hb + ((size_t)(kk * 4 + q) * 64 + arow) * 8);
        }

        f32x4 acc0  = {bias0, bias0, bias0, bias0};   // tile0: [f|i]
        f32x4 acc1  = {bias1, bias1, bias1, bias1};   // tile1: [o|g]
        f32x4 acc0b = {0.f, 0.f, 0.f, 0.f};
        f32x4 acc1b = {0.f, 0.f, 0.f, 0.f};
        #pragma unroll
        for (int kk = 0; kk < 32; kk += 2) {
            s16x8 w00 = *(const s16x8*)(&Wl[cc][kk * 32 + q * 8]);
            s16x8 w10 = *(const s16x8*)(&Wl[16 + cc][kk * 32 + q * 8]);
            acc0  = __builtin_amdgcn_mfma_f32_16x16x32_bf16(af[kk], w00, acc0, 0, 0, 0);
            acc1  = __builtin_amdgcn_mfma_f32_16x16x32_bf16(af[kk], w10, acc1, 0, 0, 0);
            s16x8 w01 = *(const s16x8*)(&Wl[cc][(kk + 1) * 32 + q * 8]);
            s16x8 w11 = *(const s16x8*)(&Wl[16 + cc][(kk + 1) * 32 + q * 8]);
            acc0b = __builtin_amdgcn_mfma_f32_16x16x32_bf16(af[kk + 1], w01, acc0b, 0, 0, 0);
            acc1b = __builtin_amdgcn_mfma_f32_16x16x32_bf16(af[kk + 1], w11, acc1b, 0, 0, 0);
        }
        acc0 = acc0 + acc0b;
        acc1 = acc1 + acc1b;

        #pragma unroll
        for (int r = 0; r < 4; r++) {
            float z0 = acc0[r], z1 = acc1[r];
            float p0 = __shfl_xor(z0, 8, 64);
            float p1 = __shfl_xor(z1, 8, 64);
            float zf = (cc < 8) ? z0 : p0;
            float zi = (cc < 8) ? p0 : z0;
            float zo = (cc < 8) ? z1 : p1;
            float zg = (cc < 8) ? p1 : z1;
            float fg = sig_(zf + 1.0f);        // FORGET_BIAS
            float ig = sig_(zi);
            float og = sig_(zo);
            float gg = tanh_(zg);
            float cn = cst[r] * fg + gg * ig;
            cst[r] = cn;
            float hv = og * tanh_(cn);
            int b = bb + r;
            if (cc < 8)
                hstage[b][cc] = f2bf(hv);      // LDS staging (wave-local rows)
            if (isl1 && cc >= 8)
                out[(size_t)(t * 64 + b) * 512 + jj] = hv;
            if (t == T_STEPS - 1) {
                if (cc < 8) hs[(size_t)(isl1 * 64 + b) * 512 + jj] = hv;
                else        cs[(size_t)(isl1 * 64 + b) * 512 + jj] = cn;
            }
        }

        // wave-local flush of staged h rows -> one wide coherent store per 16B row
        {
            unsigned short* hdst = hseq + (size_t)t * 32768 + (size_t)wg * 512;
            if (lane < 16) {
                int row = wv * 16 + lane;
                s16x8 v = *(const s16x8*)(&hstage[row][0]);
                stc(hdst + (size_t)row * 8, v);
            }
        }

        // arrival: __syncthreads drains vmcnt (h stores ack'd at coherence point),
        // then one relaxed agent-scope increment per WG.  NO wbl2 / inv.
        __syncthreads();
        if (tid == 0)
            __hip_atomic_fetch_add(my_cnt + (wg & 3) * 16, 1u, __ATOMIC_RELAXED, __HIP_MEMORY_SCOPE_AGENT);
    }
}

// ---- launch -------------------------------------------------------------

extern "C" void kernel_launch(void* const* d_in, const int* in_sizes, int n_in,
                              void* d_out, int out_size, void* d_ws, size_t ws_size,
                              hipStream_t stream) {
    const float* x  = (const float*)d_in[0];
    const float* W0 = (const float*)d_in[1];
    const float* b0 = (const float*)d_in[2];
    const float* W1 = (const float*)d_in[3];
    const float* b1 = (const float*)d_in[4];
    const float* h0 = (const float*)d_in[5];
    const float* c0 = (const float*)d_in[6];
    float* out = (float*)d_out;

    char* ws = (char*)d_ws;
    unsigned short* xb  = (unsigned short*)(ws);                               // 33,554,432 B
    unsigned short* h0s = (unsigned short*)(ws + 33554432);                    // 33,554,432 B
    unsigned short* h1s = (unsigned short*)(ws + 2 * 33554432);                // 33,554,432 B
    unsigned short* WT0 = (unsigned short*)(ws + 3 * 33554432);                //  4,194,304 B
    unsigned short* WT1 = (unsigned short*)(ws + 3 * 33554432 + 4194304);      //  4,194,304 B
    unsigned short* hi0 = (unsigned short*)(ws + 3 * 33554432 + 2 * 4194304);            // 65,536 B
    unsigned short* hi1 = (unsigned short*)(ws + 3 * 33554432 + 2 * 4194304 + 65536);    // 65,536 B
    unsigned int*   cnt = (unsigned int*)(ws + 3 * 33554432 + 2 * 4194304 + 2 * 65536);  // counters

    hipMemsetAsync(cnt, 0, 1024, stream);
    k_conv_bf16<<<8192, 256, 0, stream>>>(x, xb);
    k_transpose_w<<<dim3(64, 32, 2), dim3(32, 8), 0, stream>>>(W0, W1, WT0, WT1);
    k_hinit<<<256, 256, 0, stream>>>(h0, hi0, hi1);

    float* hs = out + 16777216;            // [2][64][512]
    float* cs = hs + 65536;                // [2][64][512]
    k_lstm_fused<<<128, 256, 0, stream>>>(xb, hi0, hi1, WT0, WT1, b0, b1, c0,
                                          h0s, h1s, out, hs, cs, cnt);
}